// Round 4
// baseline (13555.058 us; speedup 1.0000x reference)
//
#include <hip/hip_runtime.h>
#include <hip/hip_bf16.h>

#define B_ 16
#define T_ 32
#define S_ 256
#define K_ 8
#define L_ 64
#define V_ 32000
#define VX_ 32050
#define NEG_ -1e10f

__device__ __forceinline__ float fsigmoid(float x){ return 1.f/(1.f+__expf(-x)); }
__device__ __forceinline__ float ftanh(float x){ float e=__expf(2.f*x); return 1.f - 2.f/(e+1.f); }

// ---------------- embed fill: X[t][b][0:512] = embedding[tgt[b][t]] ----------------
__global__ void k_embed(const float* __restrict__ emb, const int* __restrict__ tgt, float* __restrict__ X){
  int idx = blockIdx.x*256 + threadIdx.x;
  if (idx >= T_*B_*512) return;
  int t = idx >> 13; int b = (idx >> 9) & 15; int e = idx & 511;
  int tok = tgt[b*T_ + t];
  X[(size_t)(t*B_+b)*1536 + e] = emb[(size_t)tok*512 + e];
}

// ---------------- generic f32 GEMM: C[M,N] = A[M,K](ldA) * W[N,K](ldW)^T + bias ----------------
template<bool PERM>
__global__ __launch_bounds__(256) void k_gemm(const float* __restrict__ A, int ldA,
    const float* __restrict__ W, int ldW,
    const float* __restrict__ bias, float* __restrict__ C, int K, int ldC){
  __shared__ float As[16][132];
  __shared__ float Ws[16][68];
  const int m0 = blockIdx.x*128, n0 = blockIdx.y*64;
  const int tid = threadIdx.x;
  const int tm = tid & 15, tn = tid >> 4;
  float acc[8][4];
#pragma unroll
  for (int i=0;i<8;++i)
#pragma unroll
    for(int j=0;j<4;++j) acc[i][j]=0.f;
  for (int k0=0;k0<K;k0+=16){
#pragma unroll
    for (int rr=0;rr<2;++rr){
      int f = tid + rr*256;
      int mm = f >> 2, kc = f & 3;
      const float4 v = *(const float4*)(A + (size_t)(m0+mm)*ldA + k0 + kc*4);
      As[kc*4+0][mm]=v.x; As[kc*4+1][mm]=v.y; As[kc*4+2][mm]=v.z; As[kc*4+3][mm]=v.w;
    }
    {
      int nn = tid >> 2, kc = tid & 3;
      const float4 v = *(const float4*)(W + (size_t)(n0+nn)*ldW + k0 + kc*4);
      Ws[kc*4+0][nn]=v.x; Ws[kc*4+1][nn]=v.y; Ws[kc*4+2][nn]=v.z; Ws[kc*4+3][nn]=v.w;
    }
    __syncthreads();
#pragma unroll
    for (int kk=0;kk<16;++kk){
      float a[8], w[4];
      float4 a0 = *(const float4*)&As[kk][tm*8];
      float4 a1 = *(const float4*)&As[kk][tm*8+4];
      float4 w0 = *(const float4*)&Ws[kk][tn*4];
      a[0]=a0.x;a[1]=a0.y;a[2]=a0.z;a[3]=a0.w;a[4]=a1.x;a[5]=a1.y;a[6]=a1.z;a[7]=a1.w;
      w[0]=w0.x;w[1]=w0.y;w[2]=w0.z;w[3]=w0.w;
#pragma unroll
      for (int i=0;i<8;++i)
#pragma unroll
        for (int j=0;j<4;++j) acc[i][j] += a[i]*w[j];
    }
    __syncthreads();
  }
#pragma unroll
  for (int i=0;i<8;++i){
    int m = m0 + tm*8 + i;
    size_t row = PERM ? (size_t)((m&15)*T_ + (m>>4)) : (size_t)m;
#pragma unroll
    for (int j=0;j<4;++j){
      int n = n0 + tn*4 + j;
      C[row*(size_t)ldC + n] = acc[i][j] + (bias ? bias[n] : 0.f);
    }
  }
}

// ---------------- per-batch persistent recurrence: 16 blocks x 512 threads, NO grid sync ----------------
struct RP2 {
  const float *inith, *src, *smask, *kgh, *kmask;
  const float *Wq_c, *Wq_k, *Vw_c, *bV_c, *Vw_k, *bV_k;
  const float *W_ih, *W_hh, *b_ih, *b_hh;
  const float *PVS, *PVK, *GIY;
  float *Xb, *S_all, *KW;
};

__global__ __launch_bounds__(512) void k_recur2(RP2 p){
  const int b = blockIdx.x, tid = threadIdx.x;
  __shared__ float hS[512], hqcS[512], hqkS[512], cS[512], kS[512];
  __shared__ float vwcS[512], vwkS[512];
  __shared__ float eSS[256], wS[256], red[256];
  __shared__ float ekS[8], kwS[8];

  vwcS[tid] = p.Vw_c[tid];
  vwkS[tid] = p.Vw_k[tid];
  hS[tid]   = p.inith[b*512 + tid];
  const float bVc = p.bV_c[0], bVk = p.bV_k[0];
  __syncthreads();

  for (int t=0; t<T_; ++t){
    size_t rbase = (size_t)t*16 + b;

    // ---- Phase 1: hq_c[tid], hq_k[tid] = Wq_{c,k}[tid,:] . h ----
    {
      const float* wc = p.Wq_c + (size_t)tid*512;
      const float* wk = p.Wq_k + (size_t)tid*512;
      float sc=0.f, sk=0.f;
#pragma unroll 4
      for (int i=0;i<128;++i){
        float4 a = *(const float4*)(wc + i*4);
        float4 d = *(const float4*)(wk + i*4);
        float h0=hS[i*4], h1=hS[i*4+1], h2=hS[i*4+2], h3=hS[i*4+3];
        sc += a.x*h0 + a.y*h1 + a.z*h2 + a.w*h3;
        sk += d.x*h0 + d.y*h1 + d.z*h2 + d.w*h3;
      }
      hqcS[tid] = sc; hqkS[tid] = sk;
    }
    __syncthreads();

    // ---- Phase 2: e_src (2 threads per sI) + e_kg (wave 7) ----
    {
      int sI = tid >> 1, half = tid & 1, k0 = half*256;
      const float* pv = p.PVS + ((size_t)(b*S_ + sI))*512 + k0;
      float s = 0.f;
#pragma unroll 2
      for (int m=0;m<64;++m){
        float4 v = *(const float4*)(pv + m*4);
        int i0 = k0 + m*4;
        s += ftanh(v.x+hqcS[i0+0])*vwcS[i0+0] + ftanh(v.y+hqcS[i0+1])*vwcS[i0+1]
           + ftanh(v.z+hqcS[i0+2])*vwcS[i0+2] + ftanh(v.w+hqcS[i0+3])*vwcS[i0+3];
      }
      s += __shfl_xor(s, 1, 64);
      if (half == 0){
        float v = s + bVc;
        if (p.smask[b*S_ + sI] == 0.f) v += NEG_;
        eSS[sI] = v;
      }
      if (tid >= 448){
        int local = tid-448, key = local>>3, part = local&7;
        const float* pvk = p.PVK + ((size_t)(b*K_ + key))*512 + part*64;
        const float* hq  = hqkS + part*64;
        const float* vw  = vwkS + part*64;
        float s2 = 0.f;
#pragma unroll
        for (int m=0;m<16;++m){
          float4 v = *(const float4*)(pvk + m*4);
          int i0 = m*4;
          s2 += ftanh(v.x+hq[i0+0])*vw[i0+0] + ftanh(v.y+hq[i0+1])*vw[i0+1]
              + ftanh(v.z+hq[i0+2])*vw[i0+2] + ftanh(v.w+hq[i0+3])*vw[i0+3];
        }
        s2 += __shfl_down(s2, 4, 8);
        s2 += __shfl_down(s2, 2, 8);
        s2 += __shfl_down(s2, 1, 8);
        if (part == 0){
          float v = s2 + bVk;
          if (p.kmask[b*K_ + key] == 0.f) v += NEG_;
          ekS[key] = v;
        }
      }
    }
    __syncthreads();

    // ---- Phase 3: softmax over eSS[256]; kg softmax by tid==511 ----
    if (tid < 256) red[tid] = eSS[tid];
    if (tid == 511){
      float mk = -1e30f;
#pragma unroll
      for (int k=0;k<8;++k) mk = fmaxf(mk, ekS[k]);
      float z = 0.f; float tmp[8];
#pragma unroll
      for (int k=0;k<8;++k){ tmp[k] = __expf(ekS[k]-mk); z += tmp[k]; }
      float iz = 1.f/z;
#pragma unroll
      for (int k=0;k<8;++k){ kwS[k] = tmp[k]*iz; p.KW[t*128 + b*8 + k] = tmp[k]*iz; }
    }
    __syncthreads();
    for (int s=128;s>0;s>>=1){ if (tid<s) red[tid]=fmaxf(red[tid],red[tid+s]); __syncthreads(); }
    float M = red[0];
    __syncthreads();
    if (tid < 256){ float ex = __expf(eSS[tid]-M); wS[tid] = ex; red[tid] = ex; }
    __syncthreads();
    for (int s=128;s>0;s>>=1){ if (tid<s) red[tid]+=red[tid+s]; __syncthreads(); }
    float Z = red[0];
    __syncthreads();
    if (tid < 256) wS[tid] = wS[tid] / Z;
    __syncthreads();

    // ---- Phase 4: c_t[tid], k_t[tid] ----
    {
      float c = 0.f;
      const float* sp = p.src + (size_t)b*S_*512 + tid;
#pragma unroll 8
      for (int s2=0;s2<256;++s2) c += wS[s2] * sp[(size_t)s2*512];
      float kt = 0.f;
#pragma unroll
      for (int k=0;k<8;++k) kt += kwS[k] * p.kgh[((size_t)(b*8+k))*512 + tid];
      cS[tid] = c; kS[tid] = kt;
      p.Xb[rbase*1536 + 512 + tid] = c;
      p.Xb[rbase*1536 + 1024 + tid] = kt;
    }
    __syncthreads();

    // ---- Phase 5: GRU — thread owns column j=tid (rows j, 512+j, 1024+j) ----
    {
      float gi[3], gh[3];
#pragma unroll
      for (int g=0; g<3; ++g){
        int row = g*512 + tid;
        const float* wr = p.W_ih + (size_t)row*1536 + 512;
        float s = 0.f;
#pragma unroll 4
        for (int i=0;i<128;++i){
          float4 w = *(const float4*)(wr + i*4);
          s += w.x*cS[i*4] + w.y*cS[i*4+1] + w.z*cS[i*4+2] + w.w*cS[i*4+3];
        }
        const float* wr2 = wr + 512;
#pragma unroll 4
        for (int i=0;i<128;++i){
          float4 w = *(const float4*)(wr2 + i*4);
          s += w.x*kS[i*4] + w.y*kS[i*4+1] + w.z*kS[i*4+2] + w.w*kS[i*4+3];
        }
        const float* wh = p.W_hh + (size_t)row*512;
        float s2 = 0.f;
#pragma unroll 4
        for (int i=0;i<128;++i){
          float4 w = *(const float4*)(wh + i*4);
          s2 += w.x*hS[i*4] + w.y*hS[i*4+1] + w.z*hS[i*4+2] + w.w*hS[i*4+3];
        }
        gi[g] = s  + p.GIY[rbase*1536 + row] + p.b_ih[row];
        gh[g] = s2 + p.b_hh[row];
      }
      float r = fsigmoid(gi[0] + gh[0]);
      float z = fsigmoid(gi[1] + gh[1]);
      float n = ftanh(gi[2] + r*gh[2]);
      float hnew = (1.f - z)*n + z*hS[tid];
      p.S_all[rbase*512 + tid] = hnew;
      __syncthreads();
      hS[tid] = hnew;
      __syncthreads();
    }
  }
}

// ---------------- build CAT4 = [s, c, k, kf] (512 x 2048) ----------------
__global__ void k_cat4(const float* __restrict__ S_all, const float* __restrict__ X,
    const float* __restrict__ kgf, float* __restrict__ CAT){
  int idx = blockIdx.x*256 + threadIdx.x;
  if (idx >= 512*2048) return;
  int r = idx >> 11, c = idx & 2047;
  float v;
  if (c < 512) v = S_all[(size_t)r*512 + c];
  else if (c < 1536) v = X[(size_t)r*1536 + c];
  else v = kgf[(r & 15)*512 + (c - 1536)];
  CAT[idx] = v;
}

// ---------------- ptr = sigmoid([c,s,y,kf,k] . Wptr + bptr) ----------------
__global__ __launch_bounds__(256) void k_ptr(const float* __restrict__ X, const float* __restrict__ S_all,
    const float* __restrict__ kgf, const float* __restrict__ Wptr, const float* __restrict__ bptr,
    float* __restrict__ PTR){
  int r = blockIdx.x*4 + (threadIdx.x >> 6);
  int lane = threadIdx.x & 63;
  const float* seg[5];
  seg[0] = X + (size_t)r*1536 + 512;
  seg[1] = S_all + (size_t)r*512;
  seg[2] = X + (size_t)r*1536;
  seg[3] = kgf + (r & 15)*512;
  seg[4] = X + (size_t)r*1536 + 1024;
  float s = 0.f;
#pragma unroll
  for (int g=0; g<5; ++g){
    const float* p = seg[g];
    const float* w = Wptr + g*512;
#pragma unroll
    for (int m=0;m<8;++m){ int i = lane + m*64; s += p[i]*w[i]; }
  }
#pragma unroll
  for (int off=32;off>0;off>>=1) s += __shfl_down(s, off, 64);
  if (lane == 0) PTR[r] = fsigmoid(s + bptr[0]);
}

// ---------------- softmax over V, * ptr, zero extras ----------------
__global__ __launch_bounds__(256) void k_softmax(float* __restrict__ out, const float* __restrict__ PTR){
  int orow = blockIdx.x;
  int b = orow >> 5, t = orow & 31;
  int r = t*16 + b;
  float* f = out + (size_t)orow * VX_;
  __shared__ float red[256];
  int tid = threadIdx.x;
  float lm = -1e30f;
  for (int v = tid; v < V_; v += 256) lm = fmaxf(lm, f[v]);
  red[tid] = lm; __syncthreads();
  for (int s=128;s>0;s>>=1){ if (tid<s) red[tid]=fmaxf(red[tid],red[tid+s]); __syncthreads(); }
  float M = red[0]; __syncthreads();
  float ls = 0.f;
  for (int v = tid; v < V_; v += 256){ float e2 = __expf(f[v]-M); f[v] = e2; ls += e2; }
  red[tid] = ls; __syncthreads();
  for (int s=128;s>0;s>>=1){ if (tid<s) red[tid]+=red[tid+s]; __syncthreads(); }
  float scale = PTR[r] / red[0];
  for (int v = tid; v < V_; v += 256) f[v] *= scale;
  for (int v = V_ + tid; v < VX_; v += 256) f[v] = 0.f;
}

// ---------------- copy-dist + scatter ----------------
__global__ __launch_bounds__(256) void k_scatter(const float* __restrict__ Q, const float* __restrict__ kgo,
    const float* __restrict__ kpmask, const int* __restrict__ kev, const float* __restrict__ KW,
    const float* __restrict__ PTR, float* __restrict__ out){
  int bid = blockIdx.x;
  int tg = bid & 3, k = (bid >> 2) & 7, b = bid >> 5;
  int tid = threadIdx.x;
  int l = tid >> 2, qtr = tid & 3;
  __shared__ float qs[512];
  __shared__ float part[256];
  const float* kgrow = kgo + (size_t)((b*8 + k)*64 + l) * 512;
  for (int tt=0; tt<8; ++tt){
    int t = tg*8 + tt;
    int r = t*16 + b;
    int orow = b*32 + t;
    qs[tid] = Q[(size_t)r*512 + tid];
    qs[256 + tid] = Q[(size_t)r*512 + 256 + tid];
    __syncthreads();
    float p = 0.f;
    const float4* q4 = (const float4*)(qs) + qtr*32;
    const float4* k4 = (const float4*)(kgrow) + qtr*32;
#pragma unroll 4
    for (int m=0;m<32;++m){ float4 a=q4[m], c=k4[m]; p += a.x*c.x+a.y*c.y+a.z*c.z+a.w*c.w; }
    part[tid] = p;
    __syncthreads();
    if (tid < 64){
      float ev = part[tid*4]+part[tid*4+1]+part[tid*4+2]+part[tid*4+3];
      if (kpmask[(b*8+k)*64 + tid] == 0.f) ev += NEG_;
      float mx = ev;
#pragma unroll
      for (int off=32;off>0;off>>=1) mx = fmaxf(mx, __shfl_xor(mx, off, 64));
      float ex = __expf(ev - mx);
      float z = ex;
#pragma unroll
      for (int off=32;off>0;off>>=1) z += __shfl_xor(z, off, 64);
      float val = (ex/z) * KW[t*128 + b*8 + k] * (1.f - PTR[r]);
      atomicAdd(out + (size_t)orow*VX_ + kev[(b*8+k)*64 + tid], val);
    }
    __syncthreads();
  }
}

// ---------------- final normalize ----------------
__global__ __launch_bounds__(256) void k_norm(float* __restrict__ out){
  int orow = blockIdx.x;
  float* f = out + (size_t)orow*VX_;
  __shared__ float red[256];
  int tid = threadIdx.x;
  float ls = 0.f;
  for (int v=tid; v<VX_; v+=256) ls += f[v];
  red[tid]=ls; __syncthreads();
  for (int s=128;s>0;s>>=1){ if (tid<s) red[tid]+=red[tid+s]; __syncthreads(); }
  float inv = 1.f/red[0];
  for (int v=tid; v<VX_; v+=256) f[v] *= inv;
}

extern "C" void kernel_launch(void* const* d_in, const int* in_sizes, int n_in,
                              void* d_out, int out_size, void* d_ws, size_t ws_size,
                              hipStream_t stream) {
  const int*   tgt   = (const int*)  d_in[0];
  const float* inith = (const float*)d_in[1];
  const float* src   = (const float*)d_in[2];
  const float* smask = (const float*)d_in[3];
  const float* kgh   = (const float*)d_in[4];
  const float* kgf   = (const float*)d_in[5];
  const float* kgo   = (const float*)d_in[6];
  const float* kmask = (const float*)d_in[7];
  const float* kpmask= (const float*)d_in[8];
  const int*   kev   = (const int*)  d_in[10];
  const float* emb   = (const float*)d_in[12];
  const float* W_ih  = (const float*)d_in[13];
  const float* W_hh  = (const float*)d_in[14];
  const float* b_ih  = (const float*)d_in[15];
  const float* b_hh  = (const float*)d_in[16];
  const float* Wq_c  = (const float*)d_in[17];
  const float* Wv_c  = (const float*)d_in[18];
  const float* bv_c  = (const float*)d_in[19];
  const float* Vw_c  = (const float*)d_in[20];
  const float* bV_c  = (const float*)d_in[21];
  const float* Wq_k  = (const float*)d_in[22];
  const float* Wv_k  = (const float*)d_in[23];
  const float* bv_k  = (const float*)d_in[24];
  const float* Vw_k  = (const float*)d_in[25];
  const float* bV_k  = (const float*)d_in[26];
  const float* W1    = (const float*)d_in[27];
  const float* b1    = (const float*)d_in[28];
  const float* W2    = (const float*)d_in[29];
  const float* b2    = (const float*)d_in[30];
  const float* Wptr  = (const float*)d_in[31];
  const float* bptr  = (const float*)d_in[32];
  const float* Wcpy  = (const float*)d_in[33];
  const float* bcpy  = (const float*)d_in[34];
  float* out = (float*)d_out;

  float* Xb    = (float*)d_ws;            // (T,B,1536)
  float* S_all = Xb    + 786432;          // (T*B,512)
  float* PVS   = S_all + 262144;          // (B,S,512)
  float* PVK   = PVS   + 2097152;         // (B,8,512)
  float* KW    = PVK   + 65536;           // (T,B,8)
  float* GIY   = KW    + 4096;            // (512,1536)
  float* CAT   = GIY   + 786432;          // (512,2048)
  float* HID   = CAT   + 1048576;         // (512,512)
  float* Qb    = HID   + 262144;          // (512,512)
  float* PTR   = Qb    + 262144;          // (512)

  // prep
  k_embed<<<(T_*B_*512+255)/256, 256, 0, stream>>>(emb, tgt, Xb);
  k_gemm<false><<<dim3(32,8), 256, 0, stream>>>(src, 512, Wv_c, 512, bv_c, PVS, 512, 512);
  k_gemm<false><<<dim3(1,8),  256, 0, stream>>>(kgh, 512, Wv_k, 512, bv_k, PVK, 512, 512);
  k_gemm<false><<<dim3(4,24), 256, 0, stream>>>(Xb, 1536, W_ih, 1536, nullptr, GIY, 512, 1536);

  // per-batch persistent recurrence (no grid sync, no fences)
  RP2 rp { inith, src, smask, kgh, kmask, Wq_c, Wq_k, Vw_c, bV_c, Vw_k, bV_k,
           W_ih, W_hh, b_ih, b_hh, PVS, PVK, GIY, Xb, S_all, KW };
  k_recur2<<<16, 512, 0, stream>>>(rp);

  // parallel epilogue
  k_cat4<<<(512*2048+255)/256, 256, 0, stream>>>(S_all, Xb, kgf, CAT);
  k_gemm<false><<<dim3(4,8),   256, 0, stream>>>(CAT, 2048, W1, 2048, b1, HID, 2048, 512);
  k_gemm<false><<<dim3(4,8),   256, 0, stream>>>(S_all, 512, Wcpy, 512, bcpy, Qb, 512, 512);
  k_ptr<<<128, 256, 0, stream>>>(Xb, S_all, kgf, Wptr, bptr, PTR);
  k_gemm<true><<<dim3(4,500),  256, 0, stream>>>(HID, 512, W2, 512, b2, out, 512, VX_);
  k_softmax<<<512, 256, 0, stream>>>(out, PTR);
  k_scatter<<<512, 256, 0, stream>>>(Qb, kgo, kpmask, kev, KW, PTR, out);
  k_norm<<<512, 256, 0, stream>>>(out);
}

// Round 5
// 3119.510 us; speedup vs baseline: 4.3453x; 4.3453x over previous
//
#include <hip/hip_runtime.h>
#include <hip/hip_bf16.h>

#define B_ 16
#define T_ 32
#define S_ 256
#define K_ 8
#define L_ 64
#define V_ 32000
#define VX_ 32050
#define NEG_ -1e10f

__device__ __forceinline__ float fsigmoid(float x){ return 1.f/(1.f+__expf(-x)); }
__device__ __forceinline__ float ftanh(float x){ float e=__expf(2.f*x); return 1.f - 2.f/(e+1.f); }

// ---------------- embed fill: X[t][b][0:512] = embedding[tgt[b][t]] ----------------
__global__ void k_embed(const float* __restrict__ emb, const int* __restrict__ tgt, float* __restrict__ X){
  int idx = blockIdx.x*256 + threadIdx.x;
  if (idx >= T_*B_*512) return;
  int t = idx >> 13; int b = (idx >> 9) & 15; int e = idx & 511;
  int tok = tgt[b*T_ + t];
  X[(size_t)(t*B_+b)*1536 + e] = emb[(size_t)tok*512 + e];
}

// ---------------- generic f32 GEMM: C[M,N] = A[M,K](ldA) * W[N,K](ldW)^T + bias ----------------
template<bool PERM>
__global__ __launch_bounds__(256) void k_gemm(const float* __restrict__ A, int ldA,
    const float* __restrict__ W, int ldW,
    const float* __restrict__ bias, float* __restrict__ C, int K, int ldC){
  __shared__ float As[16][132];
  __shared__ float Ws[16][68];
  const int m0 = blockIdx.x*128, n0 = blockIdx.y*64;
  const int tid = threadIdx.x;
  const int tm = tid & 15, tn = tid >> 4;
  float acc[8][4];
#pragma unroll
  for (int i=0;i<8;++i)
#pragma unroll
    for(int j=0;j<4;++j) acc[i][j]=0.f;
  for (int k0=0;k0<K;k0+=16){
#pragma unroll
    for (int rr=0;rr<2;++rr){
      int f = tid + rr*256;
      int mm = f >> 2, kc = f & 3;
      const float4 v = *(const float4*)(A + (size_t)(m0+mm)*ldA + k0 + kc*4);
      As[kc*4+0][mm]=v.x; As[kc*4+1][mm]=v.y; As[kc*4+2][mm]=v.z; As[kc*4+3][mm]=v.w;
    }
    {
      int nn = tid >> 2, kc = tid & 3;
      const float4 v = *(const float4*)(W + (size_t)(n0+nn)*ldW + k0 + kc*4);
      Ws[kc*4+0][nn]=v.x; Ws[kc*4+1][nn]=v.y; Ws[kc*4+2][nn]=v.z; Ws[kc*4+3][nn]=v.w;
    }
    __syncthreads();
#pragma unroll
    for (int kk=0;kk<16;++kk){
      float a[8], w[4];
      float4 a0 = *(const float4*)&As[kk][tm*8];
      float4 a1 = *(const float4*)&As[kk][tm*8+4];
      float4 w0 = *(const float4*)&Ws[kk][tn*4];
      a[0]=a0.x;a[1]=a0.y;a[2]=a0.z;a[3]=a0.w;a[4]=a1.x;a[5]=a1.y;a[6]=a1.z;a[7]=a1.w;
      w[0]=w0.x;w[1]=w0.y;w[2]=w0.z;w[3]=w0.w;
#pragma unroll
      for (int i=0;i<8;++i)
#pragma unroll
        for (int j=0;j<4;++j) acc[i][j] += a[i]*w[j];
    }
    __syncthreads();
  }
#pragma unroll
  for (int i=0;i<8;++i){
    int m = m0 + tm*8 + i;
    size_t row = PERM ? (size_t)((m&15)*T_ + (m>>4)) : (size_t)m;
#pragma unroll
    for (int j=0;j<4;++j){
      int n = n0 + tn*4 + j;
      C[row*(size_t)ldC + n] = acc[i][j] + (bias ? bias[n] : 0.f);
    }
  }
}

// ============ per-step K1: hq_c/hq_k/gh for all 16 batches; each weight row read once ============
// rows: [0,512)=Wq_c, [512,1024)=Wq_k, [1024,2560)=W_hh. grid 160 x 256. thread=(rowlocal, b).
__global__ __launch_bounds__(256) void k_qgh(const float* __restrict__ hsrc,
    const float* __restrict__ Wq_c, const float* __restrict__ Wq_k,
    const float* __restrict__ W_hh, const float* __restrict__ b_hh,
    float* __restrict__ HQC, float* __restrict__ HQK, float* __restrict__ GH){
  __shared__ float hS[16*516];   // pad 516: 16B-aligned rows, 2-way-bank only
  const int tid = threadIdx.x;
  for (int i=tid; i<8192; i+=256) hS[(i>>9)*516 + (i&511)] = hsrc[i];
  __syncthreads();
  const int rl = tid >> 4, b = tid & 15;
  const int R = blockIdx.x*16 + rl;
  const float* wrow;
  if (R < 512)       wrow = Wq_c + (size_t)R*512;
  else if (R < 1024) wrow = Wq_k + (size_t)(R-512)*512;
  else               wrow = W_hh + (size_t)(R-1024)*512;
  const float4* w4 = (const float4*)wrow;
  const float* hb = hS + b*516;
  float s = 0.f;
#pragma unroll 8
  for (int m=0;m<128;++m){
    float4 w = w4[m];
    float4 hv = *(const float4*)(hb + m*4);
    s += w.x*hv.x + w.y*hv.y + w.z*hv.z + w.w*hv.w;
  }
  if (R < 512)       HQC[b*512 + R] = s;
  else if (R < 1024) HQK[b*512 + (R-512)] = s;
  else               GH[b*1536 + (R-1024)] = s + b_hh[R-1024];
}

// ============ per-step K2: attention energies + softmax + c_t/k_t, one block per batch ============
__global__ __launch_bounds__(1024) void k_att2(
    const float* __restrict__ HQC, const float* __restrict__ HQK,
    const float* __restrict__ Vw_c, const float* __restrict__ Vw_k,
    const float* __restrict__ bV_c, const float* __restrict__ bV_k,
    const float* __restrict__ smask, const float* __restrict__ kmask,
    const float* __restrict__ PVS, const float* __restrict__ PVK,
    const float* __restrict__ src, const float* __restrict__ kgh,
    float* __restrict__ Xbt, float* __restrict__ CK, float* __restrict__ KWt){
  const int b = blockIdx.x, tid = threadIdx.x;
  __shared__ float hqcS[512], vwcS[512], hqkS[512], vwkS[512];
  __shared__ float eS[256], wS[256], red[256];
  __shared__ float ekS[8], kwS[8];
  if (tid < 512){ hqcS[tid] = HQC[b*512+tid]; vwcS[tid] = Vw_c[tid]; }
  else          { hqkS[tid-512] = HQK[b*512 + tid-512]; vwkS[tid-512] = Vw_k[tid-512]; }
  __syncthreads();
  // e_src: 4 threads per source position
  {
    int s_i = tid >> 2, q = tid & 3;
    const float4* pv4 = (const float4*)(PVS + ((size_t)(b*S_ + s_i))*512 + q*128);
    float p = 0.f;
#pragma unroll 8
    for (int m=0;m<32;++m){
      float4 v = pv4[m];
      int i0 = q*128 + m*4;
      p += ftanh(v.x+hqcS[i0+0])*vwcS[i0+0] + ftanh(v.y+hqcS[i0+1])*vwcS[i0+1]
         + ftanh(v.z+hqcS[i0+2])*vwcS[i0+2] + ftanh(v.w+hqcS[i0+3])*vwcS[i0+3];
    }
    p += __shfl_xor(p, 1, 64);
    p += __shfl_xor(p, 2, 64);
    if (q == 0){
      float v = p + bV_c[0];
      if (smask[b*S_ + s_i] == 0.f) v += NEG_;
      eS[s_i] = v;
    }
    if (tid >= 960){  // e_kg: 8 keys x 8 threads (last wave)
      int local = tid - 960, key = local >> 3, part = local & 7;
      const float4* pk4 = (const float4*)(PVK + ((size_t)(b*K_ + key))*512 + part*64);
      float p2 = 0.f;
#pragma unroll
      for (int m=0;m<16;++m){
        float4 v = pk4[m];
        int i0 = part*64 + m*4;
        p2 += ftanh(v.x+hqkS[i0+0])*vwkS[i0+0] + ftanh(v.y+hqkS[i0+1])*vwkS[i0+1]
            + ftanh(v.z+hqkS[i0+2])*vwkS[i0+2] + ftanh(v.w+hqkS[i0+3])*vwkS[i0+3];
      }
      p2 += __shfl_down(p2, 4, 64);
      p2 += __shfl_down(p2, 2, 64);
      p2 += __shfl_down(p2, 1, 64);
      if (part == 0){
        float v = p2 + bV_k[0];
        if (kmask[b*K_ + key] == 0.f) v += NEG_;
        ekS[key] = v;
      }
    }
  }
  __syncthreads();
  // softmax over eS[256] (unnormalized weights kept; scale at the end)
  if (tid < 256) red[tid] = eS[tid];
  __syncthreads();
  for (int s=128;s>0;s>>=1){ if (tid<s) red[tid]=fmaxf(red[tid],red[tid+s]); __syncthreads(); }
  float M = red[0];
  __syncthreads();
  if (tid < 256){ float ex = __expf(eS[tid]-M); wS[tid] = ex; red[tid] = ex; }
  if (tid == 0){
    float mk = -1e30f;
#pragma unroll
    for (int k=0;k<8;++k) mk = fmaxf(mk, ekS[k]);
    float z = 0.f; float tmp[8];
#pragma unroll
    for (int k=0;k<8;++k){ tmp[k] = __expf(ekS[k]-mk); z += tmp[k]; }
    float iz = 1.f/z;
#pragma unroll
    for (int k=0;k<8;++k) kwS[k] = tmp[k]*iz;
  }
  __syncthreads();
  for (int s=128;s>0;s>>=1){ if (tid<s) red[tid]+=red[tid+s]; __syncthreads(); }
  float invZ = 1.f/red[0];
  // c_t (2 threads per j) and k_t
  {
    int j = tid >> 1, half = tid & 1;
    const float* sp = src + (size_t)(b*S_ + half*128)*512 + j;
    float c = 0.f;
#pragma unroll 8
    for (int s2=0;s2<128;++s2) c += wS[half*128 + s2] * sp[(size_t)s2*512];
    c += __shfl_xor(c, 1, 64);
    if (half == 0){
      c *= invZ;
      float kt = 0.f;
#pragma unroll
      for (int k=0;k<8;++k) kt += kwS[k] * kgh[((size_t)(b*8+k))*512 + j];
      Xbt[(size_t)b*1536 + 512 + j]  = c;
      Xbt[(size_t)b*1536 + 1024 + j] = kt;
      CK[b*1024 + j]       = c;
      CK[b*1024 + 512 + j] = kt;
    }
    if (tid < 8) KWt[b*8 + tid] = kwS[tid];
  }
}

// ============ per-step K3: gi = W_ih[:,512:]@[c;k] (all b) + gates + h' ============
// grid 64 x 384. block owns j0=bid*8 (8 cols); rows = 3 gates x 8. thread=(rl 0..23, b 0..15).
__global__ __launch_bounds__(384) void k_gru(const float* __restrict__ CK,
    const float* __restrict__ W_ih, const float* __restrict__ GIYt,
    const float* __restrict__ b_ih, const float* __restrict__ GH,
    const float* __restrict__ hsrc, float* __restrict__ Sout){
  __shared__ float ckS[16*1028];  // pad 1028
  __shared__ float giS[24][16];
  const int tid = threadIdx.x;
  for (int i=tid; i<16384; i+=384) ckS[(i>>10)*1028 + (i&1023)] = CK[i];
  __syncthreads();
  const int rl = tid >> 4, b = tid & 15;
  const int g = rl >> 3, jl = rl & 7;
  const int j0 = blockIdx.x*8;
  const int row = g*512 + j0 + jl;
  const float4* w4 = (const float4*)(W_ih + (size_t)row*1536 + 512);
  const float* ckb = ckS + b*1028;
  float s = 0.f;
#pragma unroll 8
  for (int m=0;m<256;++m){
    float4 w = w4[m];
    float4 cv = *(const float4*)(ckb + m*4);
    s += w.x*cv.x + w.y*cv.y + w.z*cv.z + w.w*cv.w;
  }
  giS[rl][b] = s + GIYt[(size_t)b*1536 + row] + b_ih[row];
  __syncthreads();
  if (tid < 128){
    int jl2 = tid >> 4, b2 = tid & 15;
    int j = j0 + jl2;
    float gir = giS[jl2][b2], giz = giS[8+jl2][b2], gin = giS[16+jl2][b2];
    float ghr = GH[b2*1536 + j], ghz = GH[b2*1536 + 512 + j], ghn = GH[b2*1536 + 1024 + j];
    float r = fsigmoid(gir + ghr);
    float z = fsigmoid(giz + ghz);
    float n = ftanh(gin + r*ghn);
    float hold = hsrc[b2*512 + j];
    Sout[b2*512 + j] = (1.f - z)*n + z*hold;
  }
}

// ---------------- build CAT4 = [s, c, k, kf] (512 x 2048) ----------------
__global__ void k_cat4(const float* __restrict__ S_all, const float* __restrict__ X,
    const float* __restrict__ kgf, float* __restrict__ CAT){
  int idx = blockIdx.x*256 + threadIdx.x;
  if (idx >= 512*2048) return;
  int r = idx >> 11, c = idx & 2047;
  float v;
  if (c < 512) v = S_all[(size_t)r*512 + c];
  else if (c < 1536) v = X[(size_t)r*1536 + c];
  else v = kgf[(r & 15)*512 + (c - 1536)];
  CAT[idx] = v;
}

// ---------------- ptr = sigmoid([c,s,y,kf,k] . Wptr + bptr) ----------------
__global__ __launch_bounds__(256) void k_ptr(const float* __restrict__ X, const float* __restrict__ S_all,
    const float* __restrict__ kgf, const float* __restrict__ Wptr, const float* __restrict__ bptr,
    float* __restrict__ PTR){
  int r = blockIdx.x*4 + (threadIdx.x >> 6);
  int lane = threadIdx.x & 63;
  const float* seg[5];
  seg[0] = X + (size_t)r*1536 + 512;
  seg[1] = S_all + (size_t)r*512;
  seg[2] = X + (size_t)r*1536;
  seg[3] = kgf + (r & 15)*512;
  seg[4] = X + (size_t)r*1536 + 1024;
  float s = 0.f;
#pragma unroll
  for (int g=0; g<5; ++g){
    const float* p = seg[g];
    const float* w = Wptr + g*512;
#pragma unroll
    for (int m=0;m<8;++m){ int i = lane + m*64; s += p[i]*w[i]; }
  }
#pragma unroll
  for (int off=32;off>0;off>>=1) s += __shfl_down(s, off, 64);
  if (lane == 0) PTR[r] = fsigmoid(s + bptr[0]);
}

// ---------------- softmax over V, * ptr, zero extras ----------------
__global__ __launch_bounds__(256) void k_softmax(float* __restrict__ out, const float* __restrict__ PTR){
  int orow = blockIdx.x;
  int b = orow >> 5, t = orow & 31;
  int r = t*16 + b;
  float* f = out + (size_t)orow * VX_;
  __shared__ float red[256];
  int tid = threadIdx.x;
  float lm = -1e30f;
  for (int v = tid; v < V_; v += 256) lm = fmaxf(lm, f[v]);
  red[tid] = lm; __syncthreads();
  for (int s=128;s>0;s>>=1){ if (tid<s) red[tid]=fmaxf(red[tid],red[tid+s]); __syncthreads(); }
  float M = red[0]; __syncthreads();
  float ls = 0.f;
  for (int v = tid; v < V_; v += 256){ float e2 = __expf(f[v]-M); f[v] = e2; ls += e2; }
  red[tid] = ls; __syncthreads();
  for (int s=128;s>0;s>>=1){ if (tid<s) red[tid]+=red[tid+s]; __syncthreads(); }
  float scale = PTR[r] / red[0];
  for (int v = tid; v < V_; v += 256) f[v] *= scale;
  for (int v = V_ + tid; v < VX_; v += 256) f[v] = 0.f;
}

// ---------------- copy-dist + scatter ----------------
__global__ __launch_bounds__(256) void k_scatter(const float* __restrict__ Q, const float* __restrict__ kgo,
    const float* __restrict__ kpmask, const int* __restrict__ kev, const float* __restrict__ KW,
    const float* __restrict__ PTR, float* __restrict__ out){
  int bid = blockIdx.x;
  int tg = bid & 3, k = (bid >> 2) & 7, b = bid >> 5;
  int tid = threadIdx.x;
  int l = tid >> 2, qtr = tid & 3;
  __shared__ float qs[512];
  __shared__ float part[256];
  const float* kgrow = kgo + (size_t)((b*8 + k)*64 + l) * 512;
  for (int tt=0; tt<8; ++tt){
    int t = tg*8 + tt;
    int r = t*16 + b;
    int orow = b*32 + t;
    qs[tid] = Q[(size_t)r*512 + tid];
    qs[256 + tid] = Q[(size_t)r*512 + 256 + tid];
    __syncthreads();
    float p = 0.f;
    const float4* q4 = (const float4*)(qs) + qtr*32;
    const float4* k4 = (const float4*)(kgrow) + qtr*32;
#pragma unroll 4
    for (int m=0;m<32;++m){ float4 a=q4[m], c=k4[m]; p += a.x*c.x+a.y*c.y+a.z*c.z+a.w*c.w; }
    part[tid] = p;
    __syncthreads();
    if (tid < 64){
      float ev = part[tid*4]+part[tid*4+1]+part[tid*4+2]+part[tid*4+3];
      if (kpmask[(b*8+k)*64 + tid] == 0.f) ev += NEG_;
      float mx = ev;
#pragma unroll
      for (int off=32;off>0;off>>=1) mx = fmaxf(mx, __shfl_xor(mx, off, 64));
      float ex = __expf(ev - mx);
      float z = ex;
#pragma unroll
      for (int off=32;off>0;off>>=1) z += __shfl_xor(z, off, 64);
      float val = (ex/z) * KW[t*128 + b*8 + k] * (1.f - PTR[r]);
      atomicAdd(out + (size_t)orow*VX_ + kev[(b*8+k)*64 + tid], val);
    }
    __syncthreads();
  }
}

// ---------------- final normalize ----------------
__global__ __launch_bounds__(256) void k_norm(float* __restrict__ out){
  int orow = blockIdx.x;
  float* f = out + (size_t)orow*VX_;
  __shared__ float red[256];
  int tid = threadIdx.x;
  float ls = 0.f;
  for (int v=tid; v<VX_; v+=256) ls += f[v];
  red[tid]=ls; __syncthreads();
  for (int s=128;s>0;s>>=1){ if (tid<s) red[tid]+=red[tid+s]; __syncthreads(); }
  float inv = 1.f/red[0];
  for (int v=tid; v<VX_; v+=256) f[v] *= inv;
}

extern "C" void kernel_launch(void* const* d_in, const int* in_sizes, int n_in,
                              void* d_out, int out_size, void* d_ws, size_t ws_size,
                              hipStream_t stream) {
  const int*   tgt   = (const int*)  d_in[0];
  const float* inith = (const float*)d_in[1];
  const float* src   = (const float*)d_in[2];
  const float* smask = (const float*)d_in[3];
  const float* kgh   = (const float*)d_in[4];
  const float* kgf   = (const float*)d_in[5];
  const float* kgo   = (const float*)d_in[6];
  const float* kmask = (const float*)d_in[7];
  const float* kpmask= (const float*)d_in[8];
  const int*   kev   = (const int*)  d_in[10];
  const float* emb   = (const float*)d_in[12];
  const float* W_ih  = (const float*)d_in[13];
  const float* W_hh  = (const float*)d_in[14];
  const float* b_ih  = (const float*)d_in[15];
  const float* b_hh  = (const float*)d_in[16];
  const float* Wq_c  = (const float*)d_in[17];
  const float* Wv_c  = (const float*)d_in[18];
  const float* bv_c  = (const float*)d_in[19];
  const float* Vw_c  = (const float*)d_in[20];
  const float* bV_c  = (const float*)d_in[21];
  const float* Wq_k  = (const float*)d_in[22];
  const float* Wv_k  = (const float*)d_in[23];
  const float* bv_k  = (const float*)d_in[24];
  const float* Vw_k  = (const float*)d_in[25];
  const float* bV_k  = (const float*)d_in[26];
  const float* W1    = (const float*)d_in[27];
  const float* b1    = (const float*)d_in[28];
  const float* W2    = (const float*)d_in[29];
  const float* b2    = (const float*)d_in[30];
  const float* Wptr  = (const float*)d_in[31];
  const float* bptr  = (const float*)d_in[32];
  const float* Wcpy  = (const float*)d_in[33];
  const float* bcpy  = (const float*)d_in[34];
  float* out = (float*)d_out;

  float* Xb    = (float*)d_ws;            // (T,B,1536)
  float* S_all = Xb    + 786432;          // (T*B,512)
  float* PVS   = S_all + 262144;          // (B,S,512)
  float* PVK   = PVS   + 2097152;         // (B,8,512)
  float* KW    = PVK   + 65536;           // (T,B,8)
  float* GIY   = KW    + 4096;            // (T*B,1536)
  float* HQC   = GIY   + 786432;          // (16,512)
  float* HQK   = HQC   + 8192;            // (16,512)
  float* GH    = HQK   + 8192;            // (16,1536)
  float* CK    = GH    + 24576;           // (16,1024)
  float* CAT   = CK    + 16384;           // (512,2048)
  float* HID   = CAT   + 1048576;         // (512,512)
  float* Qb    = HID   + 262144;          // (512,512)
  float* PTR   = Qb    + 262144;          // (512)

  // prep
  k_embed<<<(T_*B_*512+255)/256, 256, 0, stream>>>(emb, tgt, Xb);
  k_gemm<false><<<dim3(32,8), 256, 0, stream>>>(src, 512, Wv_c, 512, bv_c, PVS, 512, 512);
  k_gemm<false><<<dim3(1,8),  256, 0, stream>>>(kgh, 512, Wv_k, 512, bv_k, PVK, 512, 512);
  k_gemm<false><<<dim3(4,24), 256, 0, stream>>>(Xb, 1536, W_ih, 1536, nullptr, GIY, 512, 1536);

  // sequential recurrence: 3 kernels/step, each weight row read by exactly one block
  for (int t = 0; t < T_; ++t){
    const float* hsrc = (t == 0) ? inith : (S_all + (size_t)(t-1)*B_*512);
    float* Xbt  = Xb  + (size_t)t*B_*1536;
    float* GIYt = GIY + (size_t)t*B_*1536;
    float* KWt  = KW  + (size_t)t*B_*K_;
    float* St   = S_all + (size_t)t*B_*512;
    k_qgh<<<160, 256, 0, stream>>>(hsrc, Wq_c, Wq_k, W_hh, b_hh, HQC, HQK, GH);
    k_att2<<<16, 1024, 0, stream>>>(HQC, HQK, Vw_c, Vw_k, bV_c, bV_k, smask, kmask,
                                    PVS, PVK, src, kgh, Xbt, CK, KWt);
    k_gru<<<64, 384, 0, stream>>>(CK, W_ih, GIYt, b_ih, GH, hsrc, St);
  }

  // parallel epilogue
  k_cat4<<<(512*2048+255)/256, 256, 0, stream>>>(S_all, Xb, kgf, CAT);
  k_gemm<false><<<dim3(4,8),   256, 0, stream>>>(CAT, 2048, W1, 2048, b1, HID, 2048, 512);
  k_gemm<false><<<dim3(4,8),   256, 0, stream>>>(S_all, 512, Wcpy, 512, bcpy, Qb, 512, 512);
  k_ptr<<<128, 256, 0, stream>>>(Xb, S_all, kgf, Wptr, bptr, PTR);
  k_gemm<true><<<dim3(4,500),  256, 0, stream>>>(HID, 512, W2, 512, b2, out, 512, VX_);
  k_softmax<<<512, 256, 0, stream>>>(out, PTR);
  k_scatter<<<512, 256, 0, stream>>>(Qb, kgo, kpmask, kev, KW, PTR, out);
  k_norm<<<512, 256, 0, stream>>>(out);
}